// Round 10
// baseline (1579.952 us; speedup 1.0000x reference)
//
#include <hip/hip_runtime.h>
#include <hip/hip_bf16.h>

#define B_ 64
#define S_ 2048
#define T_ 256
#define CPW 16  // chains per workgroup

typedef __attribute__((ext_vector_type(8))) short bf16x8;
typedef __attribute__((ext_vector_type(4))) float f32x4;

template <int CTRL>
__device__ __forceinline__ float dpp_max(float v) {
  const int t = __builtin_amdgcn_update_dpp(0, __builtin_bit_cast(int, v), CTRL, 0xF, 0xF, true);
  return fmaxf(v, __builtin_bit_cast(float, t));
}
template <int CTRL>
__device__ __forceinline__ float dpp_add(float v) {
  const int t = __builtin_amdgcn_update_dpp(0, __builtin_bit_cast(int, v), CTRL, 0xF, 0xF, true);
  return v + __builtin_bit_cast(float, t);
}

__device__ __forceinline__ unsigned short f2bf(float f) {  // round-to-nearest-even bf16
  unsigned u = __builtin_bit_cast(unsigned, f);
  u += 0x7FFFu + ((u >> 16) & 1u);
  return (unsigned short)(u >> 16);
}

// lgkm-only barrier: LDS visibility without draining in-flight global prefetch
__device__ __forceinline__ void wg_barrier() {
  __builtin_amdgcn_sched_barrier(0);
  asm volatile("s_waitcnt lgkmcnt(0)" ::: "memory");
  __builtin_amdgcn_s_barrier();
  asm volatile("" ::: "memory");
  __builtin_amdgcn_sched_barrier(0);
}

// ---------------- numerator score: ws[b] ----------------
__global__ void crf_score(const float* __restrict__ em, const int* __restrict__ tags,
                          const int* __restrict__ mask, const float* __restrict__ trans,
                          const float* __restrict__ startt, const float* __restrict__ endt,
                          float* __restrict__ ws) {
  const int b = blockIdx.x;
  const int t = threadIdx.x;  // 256
  const int* tg = tags + b * S_;
  const int* mk = mask + b * S_;
  const float* eb = em + (size_t)b * S_ * T_;

  float sc = 0.f;
  int msum = 0;
  for (int s = t; s < S_; s += 256) {
    const int tag = tg[s];
    const int m = mk[s];
    msum += m;
    const float e = eb[(size_t)s * T_ + tag];
    if (s == 0) {
      sc += startt[tag] + e;
    } else {
      const int pt = tg[s - 1];
      sc += (trans[tag * T_ + pt] + e) * (float)m;
    }
  }
#pragma unroll
  for (int off = 32; off > 0; off >>= 1) {
    sc += __shfl_down(sc, off);
    msum += __shfl_down(msum, off);
  }
  __shared__ float ssc[4];
  __shared__ int smc[4];
  const int wv = t >> 6, ln = t & 63;
  if (ln == 0) { ssc[wv] = sc; smc[wv] = msum; }
  __syncthreads();
  if (t == 0) {
    const float s4 = (ssc[0] + ssc[1]) + (ssc[2] + ssc[3]);
    const int m4 = smc[0] + smc[1] + smc[2] + smc[3];
    const int last = tg[m4 - 1];
    ws[b] = s4 + endt[last];
  }
}

// ---------------- forward (log Z), MFMA-batched: 16 chains/WG ----------------
// 4 waves x 64 j each. Per step: Z(16x256) = X(16x256,bf16) @ W(256x256,bf16) via
// 32 mfma_f32_16x16x32_bf16 per wave (W held in 128 VGPRs). X in LDS [chain][k]
// bf16, unit-XOR swizzled (phys16Bunit = (k>>3) ^ chain) -> conflict-free b128
// A-frag reads. E gathered per-lane from global, 1-step prefetch (lgkm-only
// barrier leaves it in flight). Shared pow2 renorm (1-stale, post-E stored max),
// exact integer k_run; bf16's e8 range absorbs inter-chain drift. 1 barrier/step.
#define STEP(RB, WB)                                                              \
  {                                                                               \
    float Ec[4][4];                                                               \
    _Pragma("unroll") for (int r = 0; r < 4; ++r)                                 \
      _Pragma("unroll") for (int t = 0; t < 4; ++t)                               \
        Ec[r][t] = __expf(praw[r][t]);                                            \
    _Pragma("unroll") for (int r = 0; r < 4; ++r) {                               \
      _Pragma("unroll") for (int t = 0; t < 4; ++t)                               \
        praw[r][t] = *(const float*)(emb + bidx[r] + 64 * t);                     \
      bidx[r] += 1024;                                                            \
    }                                                                             \
    const float4 q0 = *(const float4*)&mpT[RB][0];                                \
    const float4 q1 = *(const float4*)&mpT[RB][4];                                \
    const float4 q2 = *(const float4*)&mpT[RB][8];                                \
    const float4 q3 = *(const float4*)&mpT[RB][12];                               \
    float mh = fmaxf(                                                             \
        fmaxf(fmaxf(fmaxf(q0.x, q0.y), fmaxf(q0.z, q0.w)),                        \
              fmaxf(fmaxf(q1.x, q1.y), fmaxf(q1.z, q1.w))),                       \
        fmaxf(fmaxf(fmaxf(q2.x, q2.y), fmaxf(q2.z, q2.w)),                        \
              fmaxf(fmaxf(q3.x, q3.y), fmaxf(q3.z, q3.w))));                      \
    int ue = (int)(__builtin_bit_cast(unsigned, mh) >> 23) - 127;                 \
    ue = (ue < -20) ? -20 : ue;                                                   \
    const float rs = __builtin_bit_cast(float, (unsigned)((119 - ue) << 23));     \
    k_run += ue + 8;                                                              \
    f32x4 ac0 = {0.f, 0.f, 0.f, 0.f};                                             \
    f32x4 ac1 = {0.f, 0.f, 0.f, 0.f};                                             \
    f32x4 ac2 = {0.f, 0.f, 0.f, 0.f};                                             \
    f32x4 ac3 = {0.f, 0.f, 0.f, 0.f};                                             \
    _Pragma("unroll") for (int kk = 0; kk < 8; ++kk) {                            \
      const bf16x8 av = *(const bf16x8*)(&Xl[RB][0] + raddr[kk]);                 \
      ac0 = __builtin_amdgcn_mfma_f32_16x16x32_bf16(av, wf[0][kk], ac0, 0, 0, 0); \
      ac1 = __builtin_amdgcn_mfma_f32_16x16x32_bf16(av, wf[1][kk], ac1, 0, 0, 0); \
      ac2 = __builtin_amdgcn_mfma_f32_16x16x32_bf16(av, wf[2][kk], ac2, 0, 0, 0); \
      ac3 = __builtin_amdgcn_mfma_f32_16x16x32_bf16(av, wf[3][kk], ac3, 0, 0, 0); \
    }                                                                             \
    _Pragma("unroll") for (int r = 0; r < 4; ++r) {                               \
      xf[r][0] = ac0[r] * (rs * Ec[r][0]);                                        \
      xf[r][1] = ac1[r] * (rs * Ec[r][1]);                                        \
      xf[r][2] = ac2[r] * (rs * Ec[r][2]);                                        \
      xf[r][3] = ac3[r] * (rs * Ec[r][3]);                                        \
    }                                                                             \
    float mx = fmaxf(                                                             \
        fmaxf(fmaxf(fmaxf(xf[0][0], xf[0][1]), fmaxf(xf[0][2], xf[0][3])),        \
              fmaxf(fmaxf(xf[1][0], xf[1][1]), fmaxf(xf[1][2], xf[1][3]))),       \
        fmaxf(fmaxf(fmaxf(xf[2][0], xf[2][1]), fmaxf(xf[2][2], xf[2][3])),        \
              fmaxf(fmaxf(xf[3][0], xf[3][1]), fmaxf(xf[3][2], xf[3][3]))));      \
    mx = dpp_max<0xB1>(mx);                                                       \
    mx = dpp_max<0x4E>(mx);                                                       \
    mx = dpp_max<0x141>(mx);                                                      \
    mx = dpp_max<0x140>(mx);                                                      \
    if (lo == 0) mpT[WB][w * 4 + hi] = mx;                                        \
    _Pragma("unroll") for (int r = 0; r < 4; ++r)                                 \
      _Pragma("unroll") for (int t = 0; t < 4; ++t) {                             \
        const unsigned sf = __builtin_bit_cast(unsigned, xf[r][t]);               \
        *(unsigned short*)(&Xl[WB][0] + waddr[r][t]) = (unsigned short)(sf >> 16);\
      }                                                                           \
    wg_barrier();                                                                 \
  }

__global__ __launch_bounds__(256, 1) void crf_forward(
    const float* __restrict__ em, const float* __restrict__ trans,
    const float* __restrict__ startt, const float* __restrict__ endt,
    float* __restrict__ ws) {
  const int tid = threadIdx.x;
  const int w = tid >> 6;   // wave 0..3 (j-slice 64w..64w+63)
  const int l = tid & 63;
  const int lo = l & 15;    // A-row(chain) for reads; D-col(j) for outputs
  const int hi = l >> 4;    // A k-group; D row-group (chains 4hi..4hi+3)
  const int b0 = blockIdx.x * CPW;

  __shared__ __align__(16) unsigned char Xl[2][8192];  // alpha bf16 [chain][k], swizzled
  __shared__ __align__(16) float mpT[2][16];           // 16-lane-group maxes
  __shared__ __align__(16) float fintab[4][CPW];

  // ---- one-time: W fragments (B-operand), 128 VGPRs: wf[t][kk]
  bf16x8 wf[4][8];
#pragma unroll
  for (int t = 0; t < 4; ++t) {
    const int j = 64 * w + 16 * t + lo;
#pragma unroll
    for (int kk = 0; kk < 8; ++kk) {
      bf16x8 v;
#pragma unroll
      for (int e = 0; e < 8; ++e) {
        const int k = kk * 32 + hi * 8 + e;
        v[e] = (short)f2bf(__expf(trans[k * T_ + j]));
      }
      wf[t][kk] = v;
    }
  }

  // ---- addresses (unit-XOR swizzle: phys unit = (k>>3) ^ chain)
  unsigned raddr[8];
#pragma unroll
  for (int kk = 0; kk < 8; ++kk) raddr[kk] = lo * 512 + 16 * ((4 * kk + hi) ^ lo);
  unsigned waddr[4][4];
#pragma unroll
  for (int r = 0; r < 4; ++r) {
    const int cw = hi * 4 + r;
#pragma unroll
    for (int t = 0; t < 4; ++t) {
      const int j = 64 * w + 16 * t + lo;
      waddr[r][t] = cw * 512 + 16 * (((j >> 3) ^ cw) & 31) + (j & 7) * 2;
    }
  }
  unsigned bidx[4];
#pragma unroll
  for (int r = 0; r < 4; ++r)
    bidx[r] = (unsigned)(((b0 + hi * 4 + r) * (S_ * T_) + 64 * w + lo) * 4);
  const char* emb = (const char*)em;

  // ---- init: al0 = start + em[.,0,.], exact shared max m0
  float xf[4][4];
  {
    float al[4][4];
#pragma unroll
    for (int t = 0; t < 4; ++t) {
      const float st = startt[64 * w + 16 * t + lo];
#pragma unroll
      for (int r = 0; r < 4; ++r)
        al[r][t] = st + *(const float*)(emb + bidx[r] + 64 * t);
    }
    float lm = al[0][0];
#pragma unroll
    for (int r = 0; r < 4; ++r)
#pragma unroll
      for (int t = 0; t < 4; ++t) lm = fmaxf(lm, al[r][t]);
    lm = dpp_max<0xB1>(lm);
    lm = dpp_max<0x4E>(lm);
    lm = dpp_max<0x141>(lm);
    lm = dpp_max<0x140>(lm);
    if (lo == 0) mpT[1][w * 4 + hi] = lm;
    __syncthreads();
    const float4 p0 = *(const float4*)&mpT[1][0];
    const float4 p1 = *(const float4*)&mpT[1][4];
    const float4 p2 = *(const float4*)&mpT[1][8];
    const float4 p3 = *(const float4*)&mpT[1][12];
    const float m0v = fmaxf(
        fmaxf(fmaxf(fmaxf(p0.x, p0.y), fmaxf(p0.z, p0.w)),
              fmaxf(fmaxf(p1.x, p1.y), fmaxf(p1.z, p1.w))),
        fmaxf(fmaxf(fmaxf(p2.x, p2.y), fmaxf(p2.z, p2.w)),
              fmaxf(fmaxf(p3.x, p3.y), fmaxf(p3.z, p3.w))));
    // store m0 into a shared spot we keep in register below
#pragma unroll
    for (int r = 0; r < 4; ++r)
#pragma unroll
      for (int t = 0; t < 4; ++t) xf[r][t] = __expf(al[r][t] - m0v);
    fintab[0][0] = m0v;  // stash (re-read below; avoids macro capture issues)
    float mx = xf[0][0];
#pragma unroll
    for (int r = 0; r < 4; ++r)
#pragma unroll
      for (int t = 0; t < 4; ++t) mx = fmaxf(mx, xf[r][t]);
    mx = dpp_max<0xB1>(mx);
    mx = dpp_max<0x4E>(mx);
    mx = dpp_max<0x141>(mx);
    mx = dpp_max<0x140>(mx);
    if (lo == 0) mpT[0][w * 4 + hi] = mx;
#pragma unroll
    for (int r = 0; r < 4; ++r)
#pragma unroll
      for (int t = 0; t < 4; ++t) {
        const unsigned sf = __builtin_bit_cast(unsigned, xf[r][t]);
        *(unsigned short*)(&Xl[0][0] + waddr[r][t]) = (unsigned short)(sf >> 16);
      }
  }
  __syncthreads();
  const float m0 = fintab[0][0];

  // ---- prologue E (row 1)
  float praw[4][4];
#pragma unroll
  for (int r = 0; r < 4; ++r) {
    bidx[r] += 1024;
#pragma unroll
    for (int t = 0; t < 4; ++t) praw[r][t] = *(const float*)(emb + bidx[r] + 64 * t);
    bidx[r] += 1024;  // now points at row 2
  }
  int k_run = 0;
  wg_barrier();

  // ---- main loop: 1023 pairs (s = 1..2046), then tail s = 2047
  for (int s = 1; s <= S_ - 3; s += 2) {
    STEP(0, 1)
    STEP(1, 0)
  }
  {  // tail step s = 2047: read Xl[0]/mpT[0]; no store, no barrier
    float Ec[4][4];
#pragma unroll
    for (int r = 0; r < 4; ++r)
#pragma unroll
      for (int t = 0; t < 4; ++t) Ec[r][t] = __expf(praw[r][t]);
    const float4 q0 = *(const float4*)&mpT[0][0];
    const float4 q1 = *(const float4*)&mpT[0][4];
    const float4 q2 = *(const float4*)&mpT[0][8];
    const float4 q3 = *(const float4*)&mpT[0][12];
    const float mh = fmaxf(
        fmaxf(fmaxf(fmaxf(q0.x, q0.y), fmaxf(q0.z, q0.w)),
              fmaxf(fmaxf(q1.x, q1.y), fmaxf(q1.z, q1.w))),
        fmaxf(fmaxf(fmaxf(q2.x, q2.y), fmaxf(q2.z, q2.w)),
              fmaxf(fmaxf(q3.x, q3.y), fmaxf(q3.z, q3.w))));
    int ue = (int)(__builtin_bit_cast(unsigned, mh) >> 23) - 127;
    ue = (ue < -20) ? -20 : ue;
    const float rs = __builtin_bit_cast(float, (unsigned)((119 - ue) << 23));
    k_run += ue + 8;
    f32x4 ac0 = {0.f, 0.f, 0.f, 0.f};
    f32x4 ac1 = {0.f, 0.f, 0.f, 0.f};
    f32x4 ac2 = {0.f, 0.f, 0.f, 0.f};
    f32x4 ac3 = {0.f, 0.f, 0.f, 0.f};
#pragma unroll
    for (int kk = 0; kk < 8; ++kk) {
      const bf16x8 av = *(const bf16x8*)(&Xl[0][0] + raddr[kk]);
      ac0 = __builtin_amdgcn_mfma_f32_16x16x32_bf16(av, wf[0][kk], ac0, 0, 0, 0);
      ac1 = __builtin_amdgcn_mfma_f32_16x16x32_bf16(av, wf[1][kk], ac1, 0, 0, 0);
      ac2 = __builtin_amdgcn_mfma_f32_16x16x32_bf16(av, wf[2][kk], ac2, 0, 0, 0);
      ac3 = __builtin_amdgcn_mfma_f32_16x16x32_bf16(av, wf[3][kk], ac3, 0, 0, 0);
    }
#pragma unroll
    for (int r = 0; r < 4; ++r) {
      xf[r][0] = ac0[r] * (rs * Ec[r][0]);
      xf[r][1] = ac1[r] * (rs * Ec[r][1]);
      xf[r][2] = ac2[r] * (rs * Ec[r][2]);
      xf[r][3] = ac3[r] * (rs * Ec[r][3]);
    }
  }

  // ---- epilogue: logZ[c] = m0 + k_run*ln2 + log(sum_j x[c][j]*exp(end[j]))
  float ee[4];
#pragma unroll
  for (int t = 0; t < 4; ++t) ee[t] = __expf(endt[64 * w + 16 * t + lo]);
  float fin[4];
#pragma unroll
  for (int r = 0; r < 4; ++r) {
    float f = xf[r][0] * ee[0] + xf[r][1] * ee[1] + xf[r][2] * ee[2] + xf[r][3] * ee[3];
    f = dpp_add<0xB1>(f);
    f = dpp_add<0x4E>(f);
    f = dpp_add<0x141>(f);
    f = dpp_add<0x140>(f);
    fin[r] = f;
  }
  __syncthreads();  // fintab[0][0] (m0 stash) no longer needed by others
  if (lo == 0) {
    float4 fv;
    fv.x = fin[0]; fv.y = fin[1]; fv.z = fin[2]; fv.w = fin[3];
    *(float4*)&fintab[w][hi * 4] = fv;
  }
  __syncthreads();
  if (tid < CPW) {
    const float tot = fintab[0][tid] + fintab[1][tid] + fintab[2][tid] + fintab[3][tid];
    ws[64 + b0 + tid] = m0 + (float)k_run * 0.6931471805599453f + __logf(tot);
  }
}

// ---------------- final: mean_b(score - logZ) ----------------
__global__ void crf_final(const float* __restrict__ ws, float* __restrict__ out) {
  const int t = threadIdx.x;  // 64
  float v = ws[t] - ws[64 + t];
#pragma unroll
  for (int off = 1; off <= 32; off <<= 1) v += __shfl_xor(v, off);
  if (t == 0) out[0] = v * (1.0f / 64.0f);
}

extern "C" void kernel_launch(void* const* d_in, const int* in_sizes, int n_in,
                              void* d_out, int out_size, void* d_ws, size_t ws_size,
                              hipStream_t stream) {
  const float* em = (const float*)d_in[0];
  const int* tags = (const int*)d_in[1];
  const int* mask = (const int*)d_in[2];
  const float* trans = (const float*)d_in[3];
  const float* startt = (const float*)d_in[4];
  const float* endt = (const float*)d_in[5];
  float* out = (float*)d_out;
  float* ws = (float*)d_ws;

  crf_score<<<B_, 256, 0, stream>>>(em, tags, mask, trans, startt, endt, ws);
  crf_forward<<<B_ / CPW, 256, 0, stream>>>(em, trans, startt, endt, ws);
  crf_final<<<1, 64, 0, stream>>>(ws, out);
}

// Round 11
// 1315.590 us; speedup vs baseline: 1.2009x; 1.2009x over previous
//
#include <hip/hip_runtime.h>
#include <hip/hip_bf16.h>

#define B_ 64
#define S_ 2048
#define T_ 256
#define CPW 4  // chains per workgroup

typedef __attribute__((ext_vector_type(8))) short bf16x8;
typedef __attribute__((ext_vector_type(4))) float f32x4;

template <int CTRL>
__device__ __forceinline__ float dpp_max(float v) {
  const int t = __builtin_amdgcn_update_dpp(0, __builtin_bit_cast(int, v), CTRL, 0xF, 0xF, true);
  return fmaxf(v, __builtin_bit_cast(float, t));
}
template <int CTRL>
__device__ __forceinline__ float dpp_add(float v) {
  const int t = __builtin_amdgcn_update_dpp(0, __builtin_bit_cast(int, v), CTRL, 0xF, 0xF, true);
  return v + __builtin_bit_cast(float, t);
}

__device__ __forceinline__ unsigned short f2bf(float f) {  // RNE bf16
  unsigned u = __builtin_bit_cast(unsigned, f);
  u += 0x7FFFu + ((u >> 16) & 1u);
  return (unsigned short)(u >> 16);
}

// lgkm-only barrier: LDS visibility without draining in-flight global prefetch
__device__ __forceinline__ void wg_barrier() {
  __builtin_amdgcn_sched_barrier(0);
  asm volatile("s_waitcnt lgkmcnt(0)" ::: "memory");
  __builtin_amdgcn_s_barrier();
  asm volatile("" ::: "memory");
  __builtin_amdgcn_sched_barrier(0);
}

// ---------------- numerator score: ws[b] ----------------
__global__ void crf_score(const float* __restrict__ em, const int* __restrict__ tags,
                          const int* __restrict__ mask, const float* __restrict__ trans,
                          const float* __restrict__ startt, const float* __restrict__ endt,
                          float* __restrict__ ws) {
  const int b = blockIdx.x;
  const int t = threadIdx.x;  // 256
  const int* tg = tags + b * S_;
  const int* mk = mask + b * S_;
  const float* eb = em + (size_t)b * S_ * T_;

  float sc = 0.f;
  int msum = 0;
  for (int s = t; s < S_; s += 256) {
    const int tag = tg[s];
    const int m = mk[s];
    msum += m;
    const float e = eb[(size_t)s * T_ + tag];
    if (s == 0) {
      sc += startt[tag] + e;
    } else {
      const int pt = tg[s - 1];
      sc += (trans[tag * T_ + pt] + e) * (float)m;
    }
  }
#pragma unroll
  for (int off = 32; off > 0; off >>= 1) {
    sc += __shfl_down(sc, off);
    msum += __shfl_down(msum, off);
  }
  __shared__ float ssc[4];
  __shared__ int smc[4];
  const int wv = t >> 6, ln = t & 63;
  if (ln == 0) { ssc[wv] = sc; smc[wv] = msum; }
  __syncthreads();
  if (t == 0) {
    const float s4 = (ssc[0] + ssc[1]) + (ssc[2] + ssc[3]);
    const int m4 = smc[0] + smc[1] + smc[2] + smc[3];
    const int last = tg[m4 - 1];
    ws[b] = s4 + endt[last];
  }
}

// ---------------- forward (log Z), MFMA, CPW=4, aliased A-rows ----------------
// 16 WGs x 4 waves. A-tile rows 0..15 alias chains (row&3): read addr uses lo&3 ->
// 4-lane same-address broadcast (free). Lane (lo,hi) of wave w owns outputs
// (r=0..3, j = 64w+16hi+lo): selects D-tile hi via cndmask, applies EcRs =
// exp(em - ue*ln2) (rs folded into exp), writes 4 bf16 to Xl. 2-step-ahead E
// prefetch (P0/P1 ring). Renorm: exact 1-stale pow2 from post-E stored-x max
// (r10-verified scheme), integer k_run. Depth-4 MFMA chains (2 k-halves).
#define STEP(RB, WB, P)                                                           \
  {                                                                               \
    const float4 q0 = *(const float4*)&mpT[RB][0];                                \
    const float4 q1 = *(const float4*)&mpT[RB][4];                                \
    const float4 q2 = *(const float4*)&mpT[RB][8];                                \
    const float4 q3 = *(const float4*)&mpT[RB][12];                               \
    const float mh = fmaxf(                                                       \
        fmaxf(fmaxf(fmaxf(q0.x, q0.y), fmaxf(q0.z, q0.w)),                        \
              fmaxf(fmaxf(q1.x, q1.y), fmaxf(q1.z, q1.w))),                       \
        fmaxf(fmaxf(fmaxf(q2.x, q2.y), fmaxf(q2.z, q2.w)),                        \
              fmaxf(fmaxf(q3.x, q3.y), fmaxf(q3.z, q3.w))));                      \
    int ue = (int)(__builtin_bit_cast(unsigned, mh) >> 23) - 127;                 \
    ue = (ue < -20) ? -20 : ue;                                                   \
    ue += 8;                                                                      \
    k_run += ue;                                                                  \
    const float kln = -0.6931471805599453f * (float)ue;                           \
    float EcRs[4];                                                                \
    _Pragma("unroll") for (int r = 0; r < 4; ++r)                                 \
      EcRs[r] = __expf(P[r] + kln);                                               \
    _Pragma("unroll") for (int r = 0; r < 4; ++r)                                 \
      P[r] = *(const float*)(emb + vbase[r] + rowoff);                            \
    rowoff = (rowoff < 2047u * 1024u) ? rowoff + 1024u : rowoff;                  \
    f32x4 aL0 = {0.f, 0.f, 0.f, 0.f}, aL1 = aL0, aL2 = aL0, aL3 = aL0;            \
    f32x4 aH0 = aL0, aH1 = aL0, aH2 = aL0, aH3 = aL0;                             \
    _Pragma("unroll") for (int kk = 0; kk < 4; ++kk) {                            \
      const bf16x8 av = *(const bf16x8*)(&Xl[RB][0] + raddr[kk]);                 \
      aL0 = __builtin_amdgcn_mfma_f32_16x16x32_bf16(av, wf[0][kk], aL0, 0, 0, 0); \
      aL1 = __builtin_amdgcn_mfma_f32_16x16x32_bf16(av, wf[1][kk], aL1, 0, 0, 0); \
      aL2 = __builtin_amdgcn_mfma_f32_16x16x32_bf16(av, wf[2][kk], aL2, 0, 0, 0); \
      aL3 = __builtin_amdgcn_mfma_f32_16x16x32_bf16(av, wf[3][kk], aL3, 0, 0, 0); \
    }                                                                             \
    _Pragma("unroll") for (int kk = 4; kk < 8; ++kk) {                            \
      const bf16x8 av = *(const bf16x8*)(&Xl[RB][0] + raddr[kk]);                 \
      aH0 = __builtin_amdgcn_mfma_f32_16x16x32_bf16(av, wf[0][kk], aH0, 0, 0, 0); \
      aH1 = __builtin_amdgcn_mfma_f32_16x16x32_bf16(av, wf[1][kk], aH1, 0, 0, 0); \
      aH2 = __builtin_amdgcn_mfma_f32_16x16x32_bf16(av, wf[2][kk], aH2, 0, 0, 0); \
      aH3 = __builtin_amdgcn_mfma_f32_16x16x32_bf16(av, wf[3][kk], aH3, 0, 0, 0); \
    }                                                                             \
    const f32x4 ac0 = aL0 + aH0, ac1 = aL1 + aH1, ac2 = aL2 + aH2, ac3 = aL3 + aH3; \
    _Pragma("unroll") for (int r = 0; r < 4; ++r) {                               \
      const float s01 = (hi & 1) ? ac1[r] : ac0[r];                               \
      const float s23 = (hi & 1) ? ac3[r] : ac2[r];                               \
      const float val = (hi & 2) ? s23 : s01;                                     \
      xf[r] = val * EcRs[r];                                                      \
    }                                                                             \
    float mx = fmaxf(fmaxf(xf[0], xf[1]), fmaxf(xf[2], xf[3]));                   \
    mx = dpp_max<0xB1>(mx);                                                       \
    mx = dpp_max<0x4E>(mx);                                                       \
    mx = dpp_max<0x141>(mx);                                                      \
    mx = dpp_max<0x140>(mx);                                                      \
    if (lo == 0) mpT[WB][w * 4 + hi] = mx;                                        \
    _Pragma("unroll") for (int r = 0; r < 4; ++r)                                 \
      *(unsigned short*)(&Xl[WB][0] + waddr[r]) = f2bf(xf[r]);                    \
    wg_barrier();                                                                 \
  }

__global__ __launch_bounds__(256, 1) void crf_forward(
    const float* __restrict__ em, const float* __restrict__ trans,
    const float* __restrict__ startt, const float* __restrict__ endt,
    float* __restrict__ ws) {
  const int tid = threadIdx.x;
  const int w = tid >> 6;   // wave 0..3 (j-slice 64w..64w+63)
  const int l = tid & 63;
  const int lo = l & 15;
  const int hi = l >> 4;
  const int c4 = lo & 3;    // aliased chain row for A reads
  const int b0 = blockIdx.x * CPW;

  __shared__ __align__(16) unsigned char Xl[2][2048];  // alpha bf16 [4 chains][256 k]
  __shared__ __align__(16) float mpT[2][16];           // 16-lane-group maxes
  __shared__ float fintab[4][CPW];
  __shared__ float fsum[4];

  // ---- one-time: W fragments (B-operand), 128 VGPRs
  bf16x8 wf[4][8];
#pragma unroll
  for (int t = 0; t < 4; ++t) {
    const int j = 64 * w + 16 * t + lo;
#pragma unroll
    for (int kk = 0; kk < 8; ++kk) {
      bf16x8 v;
#pragma unroll
      for (int e = 0; e < 8; ++e) {
        const int k = kk * 32 + hi * 8 + e;
        v[e] = (short)f2bf(__expf(trans[k * T_ + j]));
      }
      wf[t][kk] = v;
    }
  }

  // ---- addresses: unit-XOR swizzle by (chain<<2)
  unsigned raddr[8];
#pragma unroll
  for (int kk = 0; kk < 8; ++kk)
    raddr[kk] = (unsigned)(c4 * 512 + 16 * (((4 * kk + hi) ^ (c4 << 2)) & 31));
  const int jE = 64 * w + 16 * hi + lo;  // this lane's owned output column
  unsigned waddr[4];
#pragma unroll
  for (int r = 0; r < 4; ++r)
    waddr[r] = (unsigned)(r * 512 + 16 * (((jE >> 3) ^ (r << 2)) & 31) + (jE & 7) * 2);
  unsigned vbase[4];
#pragma unroll
  for (int r = 0; r < 4; ++r)
    vbase[r] = (unsigned)(((b0 + r) * (S_ * T_) + jE) * 4);
  const char* emb = (const char*)em;

  // ---- init: al0 = start + em[.,0,.], exact shared max m0
  float xf[4];
  float m0;
  {
    const float st = startt[jE];
    float al[4];
#pragma unroll
    for (int r = 0; r < 4; ++r) al[r] = st + *(const float*)(emb + vbase[r]);
    float lm = fmaxf(fmaxf(al[0], al[1]), fmaxf(al[2], al[3]));
    lm = dpp_max<0xB1>(lm);
    lm = dpp_max<0x4E>(lm);
    lm = dpp_max<0x141>(lm);
    lm = dpp_max<0x140>(lm);
    lm = fmaxf(lm, __shfl_xor(lm, 16));
    lm = fmaxf(lm, __shfl_xor(lm, 32));
    if (l == 0) fsum[w] = lm;
    __syncthreads();
    m0 = fmaxf(fmaxf(fsum[0], fsum[1]), fmaxf(fsum[2], fsum[3]));
#pragma unroll
    for (int r = 0; r < 4; ++r) xf[r] = __expf(al[r] - m0);
#pragma unroll
    for (int r = 0; r < 4; ++r)
      *(unsigned short*)(&Xl[0][0] + waddr[r]) = f2bf(xf[r]);
    if (tid < 16) mpT[0][tid] = 1.0f;  // global max(x0) == 1 exactly
  }
  // ---- E prefetch ring: P0 = row1, P1 = row2; rowoff -> row3
  float P0[4], P1[4];
#pragma unroll
  for (int r = 0; r < 4; ++r) {
    P0[r] = *(const float*)(emb + vbase[r] + 1024);
    P1[r] = *(const float*)(emb + vbase[r] + 2048);
  }
  unsigned rowoff = 3u * 1024u;
  int k_run = 0;
  __syncthreads();

  // ---- main loop: s = 1..2046 (pairs), tail s = 2047
  for (int p2 = 0; p2 < (S_ - 2) / 2; ++p2) {
    STEP(0, 1, P0)
    STEP(1, 0, P1)
  }
  {  // tail step s = 2047: reads Xl[0]/mpT[0]/P0; no store, no barrier
    const float4 q0 = *(const float4*)&mpT[0][0];
    const float4 q1 = *(const float4*)&mpT[0][4];
    const float4 q2 = *(const float4*)&mpT[0][8];
    const float4 q3 = *(const float4*)&mpT[0][12];
    const float mh = fmaxf(
        fmaxf(fmaxf(fmaxf(q0.x, q0.y), fmaxf(q0.z, q0.w)),
              fmaxf(fmaxf(q1.x, q1.y), fmaxf(q1.z, q1.w))),
        fmaxf(fmaxf(fmaxf(q2.x, q2.y), fmaxf(q2.z, q2.w)),
              fmaxf(fmaxf(q3.x, q3.y), fmaxf(q3.z, q3.w))));
    int ue = (int)(__builtin_bit_cast(unsigned, mh) >> 23) - 127;
    ue = (ue < -20) ? -20 : ue;
    ue += 8;
    k_run += ue;
    const float kln = -0.6931471805599453f * (float)ue;
    float EcRs[4];
#pragma unroll
    for (int r = 0; r < 4; ++r) EcRs[r] = __expf(P0[r] + kln);
    f32x4 aL0 = {0.f, 0.f, 0.f, 0.f}, aL1 = aL0, aL2 = aL0, aL3 = aL0;
    f32x4 aH0 = aL0, aH1 = aL0, aH2 = aL0, aH3 = aL0;
#pragma unroll
    for (int kk = 0; kk < 4; ++kk) {
      const bf16x8 av = *(const bf16x8*)(&Xl[0][0] + raddr[kk]);
      aL0 = __builtin_amdgcn_mfma_f32_16x16x32_bf16(av, wf[0][kk], aL0, 0, 0, 0);
      aL1 = __builtin_amdgcn_mfma_f32_16x16x32_bf16(av, wf[1][kk], aL1, 0, 0, 0);
      aL2 = __builtin_amdgcn_mfma_f32_16x16x32_bf16(av, wf[2][kk], aL2, 0, 0, 0);
      aL3 = __builtin_amdgcn_mfma_f32_16x16x32_bf16(av, wf[3][kk], aL3, 0, 0, 0);
    }
#pragma unroll
    for (int kk = 4; kk < 8; ++kk) {
      const bf16x8 av = *(const bf16x8*)(&Xl[0][0] + raddr[kk]);
      aH0 = __builtin_amdgcn_mfma_f32_16x16x32_bf16(av, wf[0][kk], aH0, 0, 0, 0);
      aH1 = __builtin_amdgcn_mfma_f32_16x16x32_bf16(av, wf[1][kk], aH1, 0, 0, 0);
      aH2 = __builtin_amdgcn_mfma_f32_16x16x32_bf16(av, wf[2][kk], aH2, 0, 0, 0);
      aH3 = __builtin_amdgcn_mfma_f32_16x16x32_bf16(av, wf[3][kk], aH3, 0, 0, 0);
    }
    const f32x4 ac0 = aL0 + aH0, ac1 = aL1 + aH1, ac2 = aL2 + aH2, ac3 = aL3 + aH3;
#pragma unroll
    for (int r = 0; r < 4; ++r) {
      const float s01 = (hi & 1) ? ac1[r] : ac0[r];
      const float s23 = (hi & 1) ? ac3[r] : ac2[r];
      const float val = (hi & 2) ? s23 : s01;
      xf[r] = val * EcRs[r];
    }
  }

  // ---- epilogue: logZ[c] = m0 + k_run*ln2 + log(sum_j x[c][j]*exp(end[j]))
  const float ee = __expf(endt[jE]);
  float fin[4];
#pragma unroll
  for (int r = 0; r < 4; ++r) {
    float f = xf[r] * ee;
    f = dpp_add<0xB1>(f);
    f = dpp_add<0x4E>(f);
    f = dpp_add<0x141>(f);
    f = dpp_add<0x140>(f);
    f += __shfl_xor(f, 16);
    f += __shfl_xor(f, 32);
    fin[r] = f;
  }
  if (l == 0) {
    float4 fv;
    fv.x = fin[0]; fv.y = fin[1]; fv.z = fin[2]; fv.w = fin[3];
    *(float4*)&fintab[w][0] = fv;
  }
  __syncthreads();
  if (tid < CPW) {
    const float tot = (fintab[0][tid] + fintab[1][tid]) + (fintab[2][tid] + fintab[3][tid]);
    ws[64 + b0 + tid] = m0 + (float)k_run * 0.6931471805599453f + __logf(tot);
  }
}

// ---------------- final: mean_b(score - logZ) ----------------
__global__ void crf_final(const float* __restrict__ ws, float* __restrict__ out) {
  const int t = threadIdx.x;  // 64
  float v = ws[t] - ws[64 + t];
#pragma unroll
  for (int off = 1; off <= 32; off <<= 1) v += __shfl_xor(v, off);
  if (t == 0) out[0] = v * (1.0f / 64.0f);
}

extern "C" void kernel_launch(void* const* d_in, const int* in_sizes, int n_in,
                              void* d_out, int out_size, void* d_ws, size_t ws_size,
                              hipStream_t stream) {
  const float* em = (const float*)d_in[0];
  const int* tags = (const int*)d_in[1];
  const int* mask = (const int*)d_in[2];
  const float* trans = (const float*)d_in[3];
  const float* startt = (const float*)d_in[4];
  const float* endt = (const float*)d_in[5];
  float* out = (float*)d_out;
  float* ws = (float*)d_ws;

  crf_score<<<B_, 256, 0, stream>>>(em, tags, mask, trans, startt, endt, ws);
  crf_forward<<<B_ / CPW, 256, 0, stream>>>(em, trans, startt, endt, ws);
  crf_final<<<1, 64, 0, stream>>>(ws, out);
}